// Round 1
// baseline (2254.328 us; speedup 1.0000x reference)
//
#include <hip/hip_runtime.h>
#include <hip/hip_bf16.h>

typedef __bf16 bf16x8 __attribute__((ext_vector_type(8)));
typedef float  f32x4  __attribute__((ext_vector_type(4)));

#define BM 128
#define BN 128
#define BK 64

// ---------- async global->LDS, 16B per lane ----------
__device__ __forceinline__ void gl_lds16(const void* gp, void* lp) {
    __builtin_amdgcn_global_load_lds(
        (__attribute__((address_space(1))) void*)(gp),
        (__attribute__((address_space(3))) void*)(lp), 16, 0, 0);
}

// ---------- pass 1a: x fp32 -> bf16 ----------
__global__ __launch_bounds__(256) void cvt_x_kernel(const float* __restrict__ x,
                                                    __bf16* __restrict__ xb, int total8) {
    for (int i = blockIdx.x * blockDim.x + threadIdx.x; i < total8;
         i += gridDim.x * blockDim.x) {
        float4 a = ((const float4*)x)[2 * i];
        float4 b = ((const float4*)x)[2 * i + 1];
        bf16x8 v;
        v[0] = (__bf16)a.x; v[1] = (__bf16)a.y; v[2] = (__bf16)a.z; v[3] = (__bf16)a.w;
        v[4] = (__bf16)b.x; v[5] = (__bf16)b.y; v[6] = (__bf16)b.z; v[7] = (__bf16)b.w;
        *(bf16x8*)(xb + (size_t)i * 8) = v;
    }
}

// ---------- pass 1b: GPTQ W4 -> bf16  (one int32 = 8 nibbles per thread-iter) ----------
__global__ __launch_bounds__(256) void dequant_w_kernel(const int* __restrict__ qw,
                                                        const int* __restrict__ qz,
                                                        const float* __restrict__ sc,
                                                        __bf16* __restrict__ wb, int total) {
    for (int i = blockIdx.x * blockDim.x + threadIdx.x; i < total;
         i += gridDim.x * blockDim.x) {
        int n = i >> 9;          // K/8 = 512 int32 per row
        int c = i & 511;
        int g = c >> 4;          // group index: (c*8)/128
        int zp = qz[(n << 2) + (g >> 3)];
        int z  = (zp >> ((g & 7) << 2)) & 0xF;
        float s  = sc[(n << 5) + g];
        float zs = (float)z * s;
        int q = qw[i];
        bf16x8 v;
#pragma unroll
        for (int j = 0; j < 8; ++j) {
            int nib = (q >> (j * 4)) & 0xF;
            v[j] = (__bf16)((float)nib * s - zs);
        }
        *(bf16x8*)(wb + (size_t)i * 8) = v;
    }
}

// ---------- pass 2: C[M,N] = A[M,K] * B[N,K]^T + bias, bf16 MFMA ----------
// MODE 0: A pre-bf16 + B pre-bf16 (gload_lds both)
// MODE 1: A fp32 reg-staged      + B pre-bf16 (gload_lds)
// MODE 2: A fp32 reg-staged      + B inline-dequant (no workspace)
template <int MODE>
__global__ __launch_bounds__(256) void gemm_kernel(
    const __bf16* __restrict__ Ab, const float* __restrict__ Af,
    const __bf16* __restrict__ Bb,
    const int* __restrict__ qw, const int* __restrict__ qz, const float* __restrict__ sc,
    const float* __restrict__ bias, float* __restrict__ C, int M, int N, int K) {
    __shared__ __bf16 As[BM * BK];
    __shared__ __bf16 Bs[BN * BK];

    const int tid = threadIdx.x;
    const int w = tid >> 6;           // wave 0..3
    const int l = tid & 63;
    const int wr = w >> 1, wc = w & 1;

    // XCD-aware bijective swizzle (gridDim divisible by 8 here)
    int nwg = gridDim.x;
    int bid = blockIdx.x;
    int swz;
    if ((nwg & 7) == 0) {
        int cpx = nwg >> 3;
        swz = (bid & 7) * cpx + (bid >> 3);
    } else {
        swz = bid;
    }
    const int ntn = N / BN;
    const int tm = swz / ntn, tn = swz % ntn;
    const long brow = (long)tm * BM, bcol = (long)tn * BN;

    f32x4 acc[4][4];
    const f32x4 zero = {0.f, 0.f, 0.f, 0.f};
#pragma unroll
    for (int m = 0; m < 4; ++m)
#pragma unroll
        for (int n = 0; n < 4; ++n) acc[m][n] = zero;

    // gload_lds staging pattern: wave w, issue i covers rows w*32+i*8 .. +8
    const int srow = w * 32 + (l >> 3);
    const int scol = (l & 7) * 8;

    for (int bk = 0; bk < K; bk += BK) {
        // ---- stage B tile [BN][BK] ----
        if constexpr (MODE < 2) {
#pragma unroll
            for (int i = 0; i < 4; ++i) {
                const __bf16* gp = Bb + (bcol + srow + i * 8) * (long)K + bk + scol;
                gl_lds16(gp, &Bs[(w * 32 + i * 8) * BK]);
            }
        } else {
            // inline dequant: thread -> row n=tid>>1, 4 consecutive int32
            int n = tid >> 1;
            long rowbase = (bcol + n) * (long)(K / 8);
            int ci = (bk >> 3) + ((tid & 1) << 2);
            int g = bk >> 7;  // BK=64 < GROUP=128, tile lies in one group
            int zp = qz[(bcol + n) * 4 + (g >> 3)];
            int z = (zp >> ((g & 7) << 2)) & 0xF;
            float s = sc[(bcol + n) * 32 + g];
            float zs = (float)z * s;
#pragma unroll
            for (int t = 0; t < 4; ++t) {
                int q = qw[rowbase + ci + t];
                bf16x8 v;
#pragma unroll
                for (int j = 0; j < 8; ++j)
                    v[j] = (__bf16)((float)((q >> (4 * j)) & 0xF) * s - zs);
                *(bf16x8*)&Bs[n * BK + ((tid & 1) * 32) + t * 8] = v;
            }
        }
        // ---- stage A tile [BM][BK] ----
        if constexpr (MODE == 0) {
#pragma unroll
            for (int i = 0; i < 4; ++i) {
                const __bf16* gp = Ab + (brow + srow + i * 8) * (long)K + bk + scol;
                gl_lds16(gp, &As[(w * 32 + i * 8) * BK]);
            }
        } else {
#pragma unroll
            for (int ch = 0; ch < 4; ++ch) {
                int e = ch * 2048 + tid * 8;
                int r = e >> 6, cc = e & 63;
                const float* gp = Af + (brow + r) * (long)K + bk + cc;
                float4 a = *(const float4*)gp;
                float4 b = *(const float4*)(gp + 4);
                bf16x8 v;
                v[0] = (__bf16)a.x; v[1] = (__bf16)a.y; v[2] = (__bf16)a.z; v[3] = (__bf16)a.w;
                v[4] = (__bf16)b.x; v[5] = (__bf16)b.y; v[6] = (__bf16)b.z; v[7] = (__bf16)b.w;
                *(bf16x8*)&As[r * BK + cc] = v;
            }
        }
        __syncthreads();  // drains vmcnt for gload_lds + orders ds_writes

        // ---- compute: 2 k-slices of 32, 4x4 fragment grid per wave ----
#pragma unroll
        for (int kk = 0; kk < 2; ++kk) {
            bf16x8 af[4], bfr[4];
#pragma unroll
            for (int m = 0; m < 4; ++m)
                af[m] = *(const bf16x8*)&As[(wr * 64 + m * 16 + (l & 15)) * BK + kk * 32 + ((l >> 4) << 3)];
#pragma unroll
            for (int n = 0; n < 4; ++n)
                bfr[n] = *(const bf16x8*)&Bs[(wc * 64 + n * 16 + (l & 15)) * BK + kk * 32 + ((l >> 4) << 3)];
#pragma unroll
            for (int m = 0; m < 4; ++m)
#pragma unroll
                for (int n = 0; n < 4; ++n)
                    acc[m][n] = __builtin_amdgcn_mfma_f32_16x16x32_bf16(af[m], bfr[n], acc[m][n], 0, 0, 0);
        }
        __syncthreads();
    }

    // ---- epilogue: C/D layout col=l&15, row=(l>>4)*4+j ----
    const int crow0 = (int)brow + wr * 64 + ((l >> 4) << 2);
    const int ccol0 = (int)bcol + wc * 64 + (l & 15);
#pragma unroll
    for (int n = 0; n < 4; ++n) {
        float bv = bias[ccol0 + n * 16];
#pragma unroll
        for (int m = 0; m < 4; ++m) {
#pragma unroll
            for (int j = 0; j < 4; ++j) {
                C[(long)(crow0 + m * 16 + j) * N + (ccol0 + n * 16)] = acc[m][n][j] + bv;
            }
        }
    }
}

extern "C" void kernel_launch(void* const* d_in, const int* in_sizes, int n_in,
                              void* d_out, int out_size, void* d_ws, size_t ws_size,
                              hipStream_t stream) {
    const float* x    = (const float*)d_in[0];
    const int*   qw   = (const int*)d_in[1];
    const int*   qz   = (const int*)d_in[2];
    const float* sc   = (const float*)d_in[3];
    const float* bias = (const float*)d_in[4];
    float* out = (float*)d_out;

    const int K = 4096, N = 16384;
    const int M = in_sizes[0] / K;  // 8192

    size_t wbytes = (size_t)N * K * 2;  // 128 MB
    size_t xbytes = (size_t)M * K * 2;  //  64 MB

    int mode;
    if (ws_size >= wbytes + xbytes) mode = 0;
    else if (ws_size >= wbytes)     mode = 1;
    else                            mode = 2;

    __bf16* Wb = (__bf16*)d_ws;
    __bf16* Xb = (__bf16*)((char*)d_ws + wbytes);

    if (mode < 2) {
        int total = N * (K / 8);
        dequant_w_kernel<<<2048, 256, 0, stream>>>(qw, qz, sc, Wb, total);
    }
    if (mode == 0) {
        int total8 = M * (K / 8);
        cvt_x_kernel<<<2048, 256, 0, stream>>>(x, Xb, total8);
    }

    dim3 grid((M / BM) * (N / BN));
    if (mode == 0)
        gemm_kernel<0><<<grid, 256, 0, stream>>>(Xb, nullptr, Wb, nullptr, nullptr, nullptr, bias, out, M, N, K);
    else if (mode == 1)
        gemm_kernel<1><<<grid, 256, 0, stream>>>(nullptr, x, Wb, nullptr, nullptr, nullptr, bias, out, M, N, K);
    else
        gemm_kernel<2><<<grid, 256, 0, stream>>>(nullptr, x, nullptr, qw, qz, sc, bias, out, M, N, K);
}